// Round 5
// baseline (142.677 us; speedup 1.0000x reference)
//
#include <hip/hip_runtime.h>
#include <hip/hip_bf16.h>
#include <stdint.h>

typedef __bf16 bf16_t;
typedef __bf16 bf16x4 __attribute__((ext_vector_type(4)));
typedef __bf16 bf16x8 __attribute__((ext_vector_type(8)));
typedef float  f32x4  __attribute__((ext_vector_type(4)));

// async global -> LDS, 16B per lane. LDS dest must be wave-uniform base (lanes scatter +16B each).
__device__ __forceinline__ void gload_lds16(const void* g, void* l) {
  __builtin_amdgcn_global_load_lds(
      (__attribute__((address_space(1))) void*)g,
      (__attribute__((address_space(3))) void*)l, 16, 0, 0);
}

// ---------------- weights cast: W_enc and W_dec in one launch ----------------
__global__ void cast_weights(const float* __restrict__ a, bf16_t* __restrict__ oa,
                             const float* __restrict__ b, bf16_t* __restrict__ ob,
                             int n4each) {
  const int i = blockIdx.x * blockDim.x + threadIdx.x;
  const float* src; bf16_t* dst; int k;
  if (i < n4each) { src = a; dst = oa; k = i; }
  else            { src = b; dst = ob; k = i - n4each; }
  f32x4 v = reinterpret_cast<const f32x4*>(src)[k];
  bf16x4 o;
  o[0] = (bf16_t)v[0]; o[1] = (bf16_t)v[1]; o[2] = (bf16_t)v[2]; o[3] = (bf16_t)v[3];
  reinterpret_cast<bf16x4*>(dst)[k] = o;
}

#define PHASE_SYNC() do { \
  __builtin_amdgcn_s_barrier(); \
  asm volatile("s_waitcnt lgkmcnt(0)" ::: "memory"); \
  __builtin_amdgcn_sched_barrier(0); \
  __builtin_amdgcn_s_setprio(1); \
} while (0)

#define PHASE_END() do { \
  __builtin_amdgcn_s_setprio(0); \
  __builtin_amdgcn_s_barrier(); \
} while (0)

#define QUAD(RH, CH, BF) do { \
  _Pragma("unroll") \
  for (int fr = 0; fr < 4; ++fr) { \
    _Pragma("unroll") \
    for (int fc = 0; fc < 2; ++fc) { \
      acc[RH][CH][fr][fc] = __builtin_amdgcn_mfma_f32_16x16x32_bf16(a[fr][0], BF[fc][0], acc[RH][CH][fr][fc], 0, 0, 0); \
      acc[RH][CH][fr][fc] = __builtin_amdgcn_mfma_f32_16x16x32_bf16(a[fr][1], BF[fc][1], acc[RH][CH][fr][fc], 0, 0, 0); \
    } \
  } \
} while (0)

// ============ GEMM1 fused (cast + relu/bias/mask + chunk cumsum), 256x256 8-phase ============
// A = x (f32) reg-staged: global f32 -> cvt once -> ds_write bf16 (T14 split).
// LDS: A bf16 dbuf 2x32KB + B bf16 dbuf 2x32KB = 128KB.
// M=32768 grid.x=128, N=512 grid.y=2, K=1024 (NT=16).
__global__ __launch_bounds__(512, 2) void gemm1_f8p(
    const float* __restrict__ x, const bf16_t* __restrict__ Wenc,
    const float* __restrict__ b_enc, const float* __restrict__ mask,
    bf16_t* __restrict__ h_out, float* __restrict__ partials)
{
  __shared__ __align__(16) char smem[131072];
  auto Al = [&](int buf) { return (bf16_t*)(smem + buf * 32768); };
  auto Bl = [&](int buf) { return (bf16_t*)(smem + 65536 + buf * 32768); };

  const int tid  = threadIdx.x;
  const int lane = tid & 63;
  const int w    = tid >> 6;
  const int wm   = w >> 2;
  const int wn   = w & 3;
  const long bm  = (long)blockIdx.x * 256;
  const long bn  = (long)blockIdx.y * 256;
  const int NT   = 16;

  f32x4  acc[2][2][4][2] = {};
  bf16x8 a[4][2], b0[2][2], b1[2][2];
  f32x4  av[8];                       // A staging registers (32 VGPR)

  // B staging (bf16, 3-bit XOR pre-swizzle on source — involution of read swizzle)
  const int scolB = (((lane & 7) ^ (lane >> 3)) << 3);
  auto stageB = [&](int t, int h) {
    bf16_t* lb = Bl(t & 1);
    #pragma unroll
    for (int c = 0; c < 2; ++c) {
      const int r0 = h * 128 + (w * 2 + c) * 8;
      gload_lds16(Wenc + (bn + r0 + (lane >> 3)) * 1024 + t * 64 + scolB, lb + r0 * 64);
    }
  };
  // A reg staging: unit u covers row u*32+(tid>>4), cols (tid&15)*4..+3 (f32x4)
  auto gaLoad = [&](int t) {
    #pragma unroll
    for (int u = 0; u < 8; ++u) {
      const int row = u * 32 + (tid >> 4);
      av[u] = *reinterpret_cast<const f32x4*>(x + (bm + row) * 1024 + t * 64 + (tid & 15) * 4);
    }
  };
  // cvt once + ds_write_b64, swizzle matches read: 8-elem block ^ (row&7)
  auto aWrite = [&](int t) {
    bf16_t* lb = Al(t & 1);
    const int c4 = tid & 15;
    #pragma unroll
    for (int u = 0; u < 8; ++u) {
      const int row = u * 32 + (tid >> 4);
      bf16x4 o;
      o[0] = (bf16_t)av[u][0]; o[1] = (bf16_t)av[u][1];
      o[2] = (bf16_t)av[u][2]; o[3] = (bf16_t)av[u][3];
      *reinterpret_cast<bf16x4*>(lb + row * 64 + ((((c4 >> 1) ^ (row & 7)) << 3) + (c4 & 1) * 4)) = o;
    }
  };

  const int fcb0 = ((((lane >> 4)    ) ^ (lane & 7)) << 3);
  const int fcb1 = ((((lane >> 4) + 4) ^ (lane & 7)) << 3);
  auto loadA = [&](int buf, int rh) {
    const bf16_t* lb = Al(buf);
    #pragma unroll
    for (int fr = 0; fr < 4; ++fr) {
      const int row = rh * 128 + wm * 64 + fr * 16 + (lane & 15);
      a[fr][0] = *reinterpret_cast<const bf16x8*>(lb + row * 64 + fcb0);
      a[fr][1] = *reinterpret_cast<const bf16x8*>(lb + row * 64 + fcb1);
    }
  };
  auto loadB = [&](int buf, int ch, bf16x8 (&bf)[2][2]) {
    const bf16_t* lb = Bl(buf);
    #pragma unroll
    for (int fc = 0; fc < 2; ++fc) {
      const int row = ch * 128 + wn * 32 + fc * 16 + (lane & 15);
      bf[fc][0] = *reinterpret_cast<const bf16x8*>(lb + row * 64 + fcb0);
      bf[fc][1] = *reinterpret_cast<const bf16x8*>(lb + row * 64 + fcb1);
    }
  };

  // ---- prologue: order B(0) -> GA(0) -> B(1) so compiler's av-wait drains B(0) ----
  __builtin_amdgcn_sched_barrier(0);
  stageB(0, 0); stageB(0, 1);   // 4 gload_lds
  gaLoad(0);                    // 8 global f32x4 -> regs
  stageB(1, 0); stageB(1, 1);   // 4 gload_lds (younger than GA)
  aWrite(0);                    // compiler waits vmcnt<=4 (B(1) younger) -> B(0) drained too
  asm volatile("s_waitcnt lgkmcnt(0)" ::: "memory");
  __builtin_amdgcn_s_barrier();

  for (int t = 0; t < NT; ++t) {
    const int buf = t & 1;
    const bool g1 = (t + 1 < NT);
    const bool g2 = (t + 2 < NT);

    // p0: issue A(t+1) global loads early; read A-h0 + B-h0
    if (g1) gaLoad(t + 1);
    loadA(buf, 0); loadB(buf, 0, b0);
    PHASE_SYNC(); QUAD(0, 0, b0); PHASE_END();

    // p1: read B-h1; stage B(t+2,0)
    loadB(buf, 1, b1);
    if (g2) stageB(t + 2, 0);
    PHASE_SYNC(); QUAD(0, 1, b1); PHASE_END();

    // p2: read A-h1; stage B(t+2,1)
    loadA(buf, 1);
    if (g2) stageB(t + 2, 1);
    PHASE_SYNC(); QUAD(1, 0, b0); PHASE_END();

    // p3: cvt + ds_write A(t+1) into the free buffer (last read tile t-1)
    if (g1) aWrite(t + 1);
    PHASE_SYNC(); QUAD(1, 1, b1);
    __builtin_amdgcn_s_setprio(0);
    asm volatile("s_waitcnt vmcnt(4)" ::: "memory");  // keep <=4 (B(t+2) halves) in flight
    __builtin_amdgcn_s_barrier();
  }
  asm volatile("s_waitcnt vmcnt(0) lgkmcnt(0)" ::: "memory");
  __builtin_amdgcn_s_barrier();
  __builtin_amdgcn_sched_barrier(0);

  // ---- fused epilogue: relu+bias+mask -> swizzled bf16 LDS tile ----
  bf16_t* tile = (bf16_t*)smem;  // [256][256] bf16, col ^ ((row>>2)&3)<<4
  float bv[2][2];
  #pragma unroll
  for (int ch = 0; ch < 2; ++ch)
    #pragma unroll
    for (int fc = 0; fc < 2; ++fc)
      bv[ch][fc] = b_enc[bn + ch * 128 + wn * 32 + fc * 16 + (lane & 15)];

  #pragma unroll
  for (int rh = 0; rh < 2; ++rh)
    #pragma unroll
    for (int fr = 0; fr < 4; ++fr) {
      const int row0 = rh * 128 + wm * 64 + fr * 16 + ((lane >> 4) << 2);
      const f32x4 mv = *reinterpret_cast<const f32x4*>(&mask[bm + row0]);
      #pragma unroll
      for (int ch = 0; ch < 2; ++ch)
        #pragma unroll
        for (int fc = 0; fc < 2; ++fc) {
          const int col = ch * 128 + wn * 32 + fc * 16 + (lane & 15);
          #pragma unroll
          for (int e = 0; e < 4; ++e) {
            const int row = row0 + e;
            float hv = acc[rh][ch][fr][fc][e] + bv[ch][fc];
            hv = (hv > 0.f ? hv : 0.f) * mv[e];
            tile[row * 256 + (col ^ (((row >> 2) & 3) << 4))] = (bf16_t)hv;
          }
        }
    }
  __syncthreads();

  // ---- column cumsum over each 128-row chunk (2 chunks per block) ----
  const int sub = tid >> 8;
  const int col = tid & 255;
  float run = 0.f;
  bf16_t* hp = h_out + (bm + sub * 128) * 512 + bn + col;
  #pragma unroll 4
  for (int s = 0; s < 128; ++s) {
    const int row = sub * 128 + s;
    run += (float)tile[row * 256 + (col ^ (((row >> 2) & 3) << 4))];
    hp[(long)s * 512] = (bf16_t)run;
  }
  partials[(blockIdx.x * 2 + sub) * 512 + bn + col] = run;
}

// ============ GEMM2: out_enc = h @ W_dec^T + P[chunk], 256x256 8-phase, deep staging ============
__global__ __launch_bounds__(512, 2) void gemm2_8p(
    const bf16_t* __restrict__ A, const bf16_t* __restrict__ B,
    const int K, const int N,
    const float* __restrict__ Padd,
    float* __restrict__ outf)
{
  __shared__ __align__(16) char smem[131072];

  const int tid  = threadIdx.x;
  const int lane = tid & 63;
  const int w    = tid >> 6;
  const int wm   = w >> 2;
  const int wn   = w & 3;
  const long bm  = (long)blockIdx.x * 256;
  const long bn  = (long)blockIdx.y * 256;
  const int NT   = K >> 6;

  const int scol = (((lane & 7) ^ (lane >> 3)) << 3);
  const int fcb0 = ((((lane >> 4)    ) ^ (lane & 7)) << 3);
  const int fcb1 = ((((lane >> 4) + 4) ^ (lane & 7)) << 3);

  f32x4  acc[2][2][4][2] = {};
  bf16x8 a[4][2], b0[2][2], b1[2][2];

  auto Albs = [&](int buf) { return (bf16_t*)(smem + buf * 65536); };
  auto Blbs = [&](int buf) { return (bf16_t*)(smem + buf * 65536 + 32768); };

  auto stageA = [&](int t, int h) {
    bf16_t* lb = Albs(t & 1);
    #pragma unroll
    for (int c = 0; c < 2; ++c) {
      const int r0 = h * 128 + (w * 2 + c) * 8;
      gload_lds16(A + (bm + r0 + (lane >> 3)) * (long)K + t * 64 + scol, lb + r0 * 64);
    }
  };
  auto stageB = [&](int t, int h) {
    bf16_t* lb = Blbs(t & 1);
    #pragma unroll
    for (int c = 0; c < 2; ++c) {
      const int r0 = h * 128 + (w * 2 + c) * 8;
      gload_lds16(B + (bn + r0 + (lane >> 3)) * (long)K + t * 64 + scol, lb + r0 * 64);
    }
  };
  auto loadA = [&](int buf, int rh) {
    const bf16_t* lb = Albs(buf);
    #pragma unroll
    for (int fr = 0; fr < 4; ++fr) {
      const int row = rh * 128 + wm * 64 + fr * 16 + (lane & 15);
      a[fr][0] = *reinterpret_cast<const bf16x8*>(lb + row * 64 + fcb0);
      a[fr][1] = *reinterpret_cast<const bf16x8*>(lb + row * 64 + fcb1);
    }
  };
  auto loadB = [&](int buf, int ch, bf16x8 (&bf)[2][2]) {
    const bf16_t* lb = Blbs(buf);
    #pragma unroll
    for (int fc = 0; fc < 2; ++fc) {
      const int row = ch * 128 + wn * 32 + fc * 16 + (lane & 15);
      bf[fc][0] = *reinterpret_cast<const bf16x8*>(lb + row * 64 + fcb0);
      bf[fc][1] = *reinterpret_cast<const bf16x8*>(lb + row * 64 + fcb1);
    }
  };

  // prologue: tile0 (8 loads/wave) + tile1 (8) -> vmcnt(8)
  __builtin_amdgcn_sched_barrier(0);
  stageA(0, 0); stageA(0, 1); stageB(0, 0); stageB(0, 1);
  stageA(1, 0); stageA(1, 1); stageB(1, 0); stageB(1, 1);
  asm volatile("s_waitcnt vmcnt(8)" ::: "memory");
  __builtin_amdgcn_s_barrier();

  for (int t = 0; t < NT; ++t) {
    const int buf = t & 1;
    const bool g2 = (t + 2 < NT);

    loadA(buf, 0); loadB(buf, 0, b0);
    PHASE_SYNC(); QUAD(0, 0, b0); PHASE_END();

    loadB(buf, 1, b1);
    if (g2) stageA(t + 2, 0);
    PHASE_SYNC(); QUAD(0, 1, b1); PHASE_END();

    loadA(buf, 1);
    if (g2) stageB(t + 2, 0);
    PHASE_SYNC(); QUAD(1, 0, b0); PHASE_END();

    if (g2) { stageA(t + 2, 1); stageB(t + 2, 1); }
    PHASE_SYNC(); QUAD(1, 1, b1);
    __builtin_amdgcn_s_setprio(0);
    if (g2) asm volatile("s_waitcnt vmcnt(8)" ::: "memory");
    else    asm volatile("s_waitcnt vmcnt(0)" ::: "memory");
    __builtin_amdgcn_s_barrier();
  }
  __builtin_amdgcn_sched_barrier(0);

  // epilogue: + per-chunk P, f32 stores (D map: col=lane&15, row=(lane>>4)*4+e)
  #pragma unroll
  for (int rh = 0; rh < 2; ++rh)
    #pragma unroll
    for (int ch = 0; ch < 2; ++ch)
      #pragma unroll
      for (int fc = 0; fc < 2; ++fc) {
        const long gc = bn + ch * 128 + wn * 32 + fc * 16 + (lane & 15);
        const float pv = Padd[(blockIdx.x * 2 + rh) * (long)N + gc];
        #pragma unroll
        for (int fr = 0; fr < 4; ++fr) {
          const long gr = bm + rh * 128 + wm * 64 + fr * 16 + ((lane >> 4) << 2);
          #pragma unroll
          for (int e = 0; e < 4; ++e)
            outf[(gr + e) * (long)N + gc] = acc[rh][ch][fr][fc][e] + pv;
        }
      }
}

// ================= small B^T GEMM for P (128x128 tile, dbuf) ==================
__global__ __launch_bounds__(256) void gemm_p(
    const bf16_t* __restrict__ A, const bf16_t* __restrict__ B,
    const int K, const int N,
    const float* __restrict__ bias,
    float* __restrict__ outf)
{
  __shared__ __align__(16) bf16_t As[2][128 * 64];
  __shared__ __align__(16) bf16_t Bs[2][128 * 64];

  const int tid  = threadIdx.x;
  const int lane = tid & 63;
  const int w    = tid >> 6;
  const int wm   = w >> 1, wn = w & 1;
  const long bm  = (long)blockIdx.x * 128;
  const long bn  = (long)blockIdx.y * 128;

  f32x4 acc[4][4] = {};

  const int srow = w * 32 + (lane >> 3);
  const int scol = (lane & 7) * 8;
  const bf16_t* Abase = A + (bm + srow) * (long)K + scol;
  const bf16_t* Bbase = B + (bn + srow) * (long)K + scol;

  auto stage = [&](bf16_t* da, bf16_t* db, int kt) {
    #pragma unroll
    for (int it = 0; it < 4; ++it) {
      gload_lds16(Abase + (long)it * 8 * K + kt, &da[(w * 32 + it * 8) * 64]);
      gload_lds16(Bbase + (long)it * 8 * K + kt, &db[(w * 32 + it * 8) * 64]);
    }
  };
  auto mfma_tile = [&](const bf16_t* Asb, const bf16_t* Bsb) {
    #pragma unroll
    for (int kk = 0; kk < 2; ++kk) {
      const int kof = kk * 32 + (lane >> 4) * 8;
      bf16x8 afr[4], bfr[4];
      #pragma unroll
      for (int i = 0; i < 4; ++i)
        afr[i] = *reinterpret_cast<const bf16x8*>(&Asb[(wm * 64 + i * 16 + (lane & 15)) * 64 + kof]);
      #pragma unroll
      for (int j = 0; j < 4; ++j)
        bfr[j] = *reinterpret_cast<const bf16x8*>(&Bsb[(wn * 64 + j * 16 + (lane & 15)) * 64 + kof]);
      #pragma unroll
      for (int i = 0; i < 4; ++i)
        #pragma unroll
        for (int j = 0; j < 4; ++j)
          acc[i][j] = __builtin_amdgcn_mfma_f32_16x16x32_bf16(afr[i], bfr[j], acc[i][j], 0, 0, 0);
    }
  };

  stage(As[0], Bs[0], 0);
  __syncthreads();
  int kt = 64;
  for (int p2 = 0; p2 < (K >> 7); ++p2) {
    if (kt < K) stage(As[1], Bs[1], kt);
    mfma_tile(As[0], Bs[0]);
    __syncthreads();
    kt += 64;
    if (kt < K) stage(As[0], Bs[0], kt);
    mfma_tile(As[1], Bs[1]);
    __syncthreads();
    kt += 64;
  }

  #pragma unroll
  for (int j = 0; j < 4; ++j) {
    const long gc = bn + wn * 64 + j * 16 + (lane & 15);
    const float addv = bias[gc];
    #pragma unroll
    for (int i = 0; i < 4; ++i) {
      const long gr0 = bm + wm * 64 + i * 16 + ((lane >> 4) << 2);
      #pragma unroll
      for (int r = 0; r < 4; ++r)
        outf[(gr0 + r) * (long)N + gc] = acc[i][j][r] + addv;
    }
  }
}

// ------------- exclusive scan over 32 chunks per (b, o); writes v (f32) -------------
__global__ void scan_chunks(const float* __restrict__ partials, bf16_t* __restrict__ prefixb,
                            float* __restrict__ v_out) {
  const int idx = blockIdx.x * blockDim.x + threadIdx.x;  // 0..4095
  const int b = idx >> 9;
  const int o = idx & 511;
  float run = 0.f;
  #pragma unroll
  for (int c = 0; c < 32; ++c) {
    const size_t off = ((size_t)(b * 32 + c)) * 512 + o;
    prefixb[off] = (bf16_t)run;
    run += partials[off];
  }
  v_out[idx] = run;
}

extern "C" void kernel_launch(void* const* d_in, const int* in_sizes, int n_in,
                              void* d_out, int out_size, void* d_ws, size_t ws_size,
                              hipStream_t stream) {
  const float* x     = (const float*)d_in[0];   // (8,4096,1024)
  const float* mask  = (const float*)d_in[1];   // (8,4096)
  const float* W_enc = (const float*)d_in[2];   // (512,1024)
  const float* b_enc = (const float*)d_in[3];   // (512,)
  const float* W_dec = (const float*)d_in[4];   // (1024,512)
  const float* b_dec = (const float*)d_in[5];   // (1024,)

  float* out     = (float*)d_out;
  float* v_out   = out;            // 8*512
  float* out_enc = out + 4096;     // 8*4096*1024

  char* ws = (char*)d_ws;
  bf16_t* Web      = (bf16_t*)ws;  ws += (size_t)512 * 1024 * 2;    // 1 MB
  bf16_t* Wdb      = (bf16_t*)ws;  ws += (size_t)1024 * 512 * 2;    // 1 MB
  bf16_t* h        = (bf16_t*)ws;  ws += (size_t)32768 * 512 * 2;   // 33.5 MB (cumulated)
  float*  partials = (float*)ws;   ws += (size_t)256 * 512 * 4;     // 512 KB
  bf16_t* prefixb  = (bf16_t*)ws;  ws += (size_t)256 * 512 * 2;     // 256 KB
  float*  P        = (float*)ws;   ws += (size_t)256 * 1024 * 4;    // 1 MB

  // 1) cast weights only (x cast is fused into GEMM1's A-staging)
  cast_weights<<<1024, 256, 0, stream>>>(W_enc, Web, W_dec, Wdb, 131072);

  // 2) GEMM1 fused: h = cumsum_128(relu(x @ W_enc^T + b_enc) * mask), partials
  gemm1_f8p<<<dim3(128, 2), 512, 0, stream>>>(x, Web, b_enc, mask, h, partials);

  // 3) scan chunk sums -> exclusive prefixes (bf16) and v (f32, output 0)
  scan_chunks<<<16, 256, 0, stream>>>(partials, prefixb, v_out);

  // 4) P[r,d] = prefix[r,:] @ W_dec[d,:] + b_dec[d]   [M=256, N=1024, K=512]
  gemm_p<<<dim3(2, 8), 256, 0, stream>>>(prefixb, Wdb, 512, 1024, b_dec, P);

  // 5) GEMM2 (8-phase, deep staging): out_enc = h_local @ W_dec^T + P[chunk]
  gemm2_8p<<<dim3(128, 4), 512, 0, stream>>>(h, Wdb, 512, 1024, P, out_enc);
}